// Round 14
// baseline (2184.041 us; speedup 1.0000x reference)
//
#include <hip/hip_runtime.h>
#include <stdint.h>

// CharRNN MI355X — r13 base (reg-resident W_hh, 16x64, split MALL barrier)
// + XCD-LOCAL DATA PATH (registration-verified), MALL barrier kept.
//   Key insight: group members (producers AND consumers of each 16-row ring
//   slice) all live on ONE XCD. r1 proved plain-store -> sc0-load is
//   coherent within an XCD; rounds 1-3 only failed on XCD-local BARRIERS.
//   So: data at the XCD L2 (plain stores / sc0 loads), barrier at the MALL
//   (r8/r12/r13-proven atomicAdd counter). Ordering: publish stores retire
//   to L2 (write-through L1) before __syncthreads completes; tid0's MALL
//   atomicAdd follows; consumers observe counter then sc0-read the same L2.
//   Groups are built from RUNTIME REGISTRATION (s_getreg XCC_ID + per-XCD
//   rank, verify 32/XCD, unanimous vote) — r1/r2-proven mechanics; on any
//   anomaly -> mode 0 = byte-identical r13 path (bid groups, agent ops).
// d_ws: proj f32 @0 (256KB) | cnt @262144 (256KB: barrier ctrs gi*8448;
//       reg dw 32768+; vote dw 33824+) | wof @524288 (128KB) | ring @1MB

#define BATCH 256
#define SEQ   512
#define HID   1024
#define VOC   64
#define EMB   256
#define FINAL_OFF (BATCH * SEQ * VOC)   // 8388608
#define RING_SLOTS 32
#define BH (BATCH * HID)
#define CNT_STRIDE 8448

typedef __attribute__((ext_vector_type(8))) short short8;
typedef __attribute__((ext_vector_type(4))) float f32x4;
typedef unsigned long long u64;

__device__ inline unsigned short f2bf(float f) {
  union { float f; unsigned u; } v; v.f = f;
  unsigned u = v.u;
  return (unsigned short)((u + 0x7FFFu + ((u >> 16) & 1u)) >> 16);  // RNE
}

// branch-free tanh: 1 - 2/(e^{2x}+1). Verified r7/r8/r12/r13.
__device__ __forceinline__ float ftanh(float v) {
  float e = __expf(2.0f * v);
  return fmaf(-2.0f, __builtin_amdgcn_rcpf(e + 1.0f), 1.0f);
}

// ---- agent-scope (MALL-point) ops — mode-0 data path + barrier -------------
__device__ inline u64 cload64(const unsigned short* p) {
  return __hip_atomic_load((const u64*)p, __ATOMIC_RELAXED,
                           __HIP_MEMORY_SCOPE_AGENT);
}
__device__ inline void cstore32(unsigned short* p, unsigned v) {
  __hip_atomic_store((unsigned*)p, v, __ATOMIC_RELAXED,
                     __HIP_MEMORY_SCOPE_AGENT);
}
// ---- XCD-local load: L1-bypass, local-L2 hit (r1-proven data path) ---------
__device__ __forceinline__ u64 ld64_sc0(const unsigned short* p) {
  u64 v;
  asm volatile("global_load_dwordx2 %0, %1, off sc0"
               : "=v"(v) : "v"(p) : "memory");
  return v;   // NOT ready until s_waitcnt vmcnt(0) + sched_barrier(0)
}

// ---------------- K1: projection table -------------------------------------
__global__ __launch_bounds__(256) void k_prep(const float* __restrict__ emb,
                                              const float* __restrict__ Wih,
                                              const float* __restrict__ bh,
                                              float* __restrict__ proj) {
  __shared__ float es[EMB];
  const int v = blockIdx.x >> 2;        // 0..63
  const int p = blockIdx.x & 3;         // h-quarter
  const int tid = threadIdx.x;
  es[tid] = emb[v * EMB + tid];
  __syncthreads();
  const int h = p * 256 + tid;
  float acc = bh[h];
  for (int e = 0; e < EMB; ++e) acc += es[e] * Wih[e * HID + h];
  proj[v * HID + h] = acc;
}

// ---------------- K1b: W_ho bf16 fragment table (r6+-proven) ----------------
__global__ __launch_bounds__(256) void k_prep2(const float* __restrict__ Who,
                                               unsigned short* __restrict__ wof) {
  const int e = blockIdx.x * 256 + threadIdx.x;   // 0..8191
  const int l15 = e & 15, vt = (e >> 4) & 3, qq = (e >> 6) & 3, kb = e >> 8;
  #pragma unroll
  for (int j = 0; j < 8; ++j)
    wof[e * 8 + j] = f2bf(Who[(kb * 32 + qq * 8 + j) * VOC + vt * 16 + l15]);
}

// ---------------- split group barrier (r12/r13, MALL point) -----------------
__device__ __forceinline__ void barrier_arrive(unsigned int* cnt_i, int tid) {
  __syncthreads();                       // release: vmcnt(0) drain, all waves
  if (tid == 0) atomicAdd(cnt_i, 1u);
}
__device__ __forceinline__ void barrier_wait(unsigned int* cnt_i, int tid,
                                             int round) {
  if (tid == 0) {
    int guard = 0;
    while (__hip_atomic_load(cnt_i, __ATOMIC_RELAXED, __HIP_MEMORY_SCOPE_AGENT)
           < 16u * (unsigned)round) {
      __builtin_amdgcn_s_sleep(1);
      if (++guard > (1 << 16)) break;    // bailout: wrong answer beats a hang
    }
  }
  __syncthreads();                       // acquire broadcast
}

// ---------------- K2: persistent recurrence + inline logits ----------------
// LDS 131072: W_hh B-frag staging (dies) -> h_lds 16 x 2064B (bank-clean).
__global__ __launch_bounds__(256, 1) void k_rnn(
    const int* __restrict__ x, const float* __restrict__ Whh,
    const float* __restrict__ proj, const unsigned short* __restrict__ wof,
    const float* __restrict__ bo, unsigned short* __restrict__ ring,
    float* __restrict__ out, float* __restrict__ final_out,
    unsigned int* __restrict__ cnt) {
  extern __shared__ char smem[];
  unsigned short* w_lds = (unsigned short*)smem;            // staging (dies)
  char*           h_lds = smem;                             // reuses region

  const int tid = threadIdx.x, bid = blockIdx.x;
  const int lane = tid & 63, wv = tid >> 6;                 // wv = nt slice
  const int l15 = lane & 15, q = lane >> 4;

  // --- Phase A: XCD registration + unanimous vote (MALL; r1/r2 mechanics) --
  int* sx = (int*)smem;                  // staging not yet written
  if (tid == 0) {
    unsigned xcc;
    asm volatile("s_getreg_b32 %0, hwreg(HW_REG_XCC_ID)" : "=s"(xcc));
    xcc &= 7u;
    unsigned* xreg = cnt + 32768;        // per-XCD counters, 128B apart
    unsigned* xtot = cnt + 33792;
    unsigned m = atomicAdd(xreg + xcc * 32, 1u);
    asm volatile("s_waitcnt vmcnt(0)" ::: "memory");
    atomicAdd(xtot, 1u);
    unsigned tot = 0; int guard = 0;
    do {
      tot = __hip_atomic_load(xtot, __ATOMIC_RELAXED, __HIP_MEMORY_SCOPE_AGENT);
      if (tot >= 256u) break;
      __builtin_amdgcn_s_sleep(2);
    } while (++guard < (1 << 16));
    int ok = (tot >= 256u) && (m < 32u);
    for (int i = 0; i < 8; ++i)
      ok &= (__hip_atomic_load(xreg + i * 32, __ATOMIC_RELAXED,
                               __HIP_MEMORY_SCOPE_AGENT) == 32u);
    // unanimous vote (guards against any per-block timeout divergence)
    if (!ok) atomicAdd(cnt + 33824, 1u);
    asm volatile("s_waitcnt vmcnt(0)" ::: "memory");
    atomicAdd(cnt + 33856, 1u);
    unsigned vt = 0; guard = 0;
    do {
      vt = __hip_atomic_load(cnt + 33856, __ATOMIC_RELAXED,
                             __HIP_MEMORY_SCOPE_AGENT);
      if (vt >= 256u) break;
      __builtin_amdgcn_s_sleep(2);
    } while (++guard < (1 << 16));
    unsigned vf = __hip_atomic_load(cnt + 33824, __ATOMIC_RELAXED,
                                    __HIP_MEMORY_SCOPE_AGENT);
    int mode = (vt >= 256u) && (vf == 0u) && ok;
    sx[0] = mode;
    sx[1] = mode ? ((int)xcc * 2 + (int)(m >> 4)) : (bid & 15);
    sx[2] = mode ? (int)(m & 15) : (bid >> 4);
  }
  __syncthreads();
  const int mode = sx[0];
  const int gi = sx[1], gj = sx[2];       // group (16 rows) / col-slice (64)
  const int row0 = gi * 16;
  __syncthreads();                        // sx read everywhere before staging

  // W_hh column slice (1024 x 64) -> LDS bf16 B-fragment order (staging).
  for (int it = 0; it < 256; ++it) {
    int u = it * 256 + tid;               // 0..65535
    int k = u >> 6, n = u & 63;           // coalesced over n
    int kb = k >> 5, qq = (k >> 3) & 3, j8 = k & 7;
    w_lds[(size_t)kb * 2048 + qq * 512 + n * 8 + j8] =
        f2bf(Whh[k * HID + gj * 64 + n]);
  }
  __syncthreads();

  // B-fragments -> REGISTERS (once; W_hh is step-invariant). 128 VGPR.
  short8 bfr[32];
  {
    const char* bbase = (const char*)w_lds + q * 1024 + (wv * 16 + l15) * 16;
    #pragma unroll
    for (int kb = 0; kb < 32; ++kb)
      bfr[kb] = *(const short8*)(bbase + (size_t)kb * 4096);
  }
  __syncthreads();                        // staging dead; region becomes h_lds

  unsigned int* cnt_i = (unsigned int*)((char*)cnt + gi * CNT_STRIDE);

  const int hcol = gj * 64 + wv * 16 + l15;
  const char* abase = h_lds + l15 * 2064 + q * 16;  // stride 2064: bank-clean
  const float bias = bo[wv * 16 + l15];
  const char* wofb = (const char*)wof + ((q * 4 + wv) * 16 + l15) * 16;

  for (int t = 0; t < SEQ; ++t) {
    int xv = (lane < 16) ? x[(row0 + lane) * SEQ + t] : 0;
    // 1) recurrence MFMA: 16x16 tile, K=1024; A from LDS, B from registers.
    f32x4 a0 = {0.f, 0.f, 0.f, 0.f}, a1 = {0.f, 0.f, 0.f, 0.f};
    f32x4 a2 = {0.f, 0.f, 0.f, 0.f}, a3 = {0.f, 0.f, 0.f, 0.f};
    if (t > 0) {
      #pragma unroll
      for (int kb = 0; kb < 32; kb += 4) {
        short8 af0 = *(const short8*)(abase + (kb + 0) * 64);
        a0 = __builtin_amdgcn_mfma_f32_16x16x32_bf16(af0, bfr[kb + 0], a0, 0, 0, 0);
        short8 af1 = *(const short8*)(abase + (kb + 1) * 64);
        a1 = __builtin_amdgcn_mfma_f32_16x16x32_bf16(af1, bfr[kb + 1], a1, 0, 0, 0);
        short8 af2 = *(const short8*)(abase + (kb + 2) * 64);
        a2 = __builtin_amdgcn_mfma_f32_16x16x32_bf16(af2, bfr[kb + 2], a2, 0, 0, 0);
        short8 af3 = *(const short8*)(abase + (kb + 3) * 64);
        a3 = __builtin_amdgcn_mfma_f32_16x16x32_bf16(af3, bfr[kb + 3], a3, 0, 0, 0);
      }
    }
    // 2) epilogue: h_t = tanh(proj[x_t] + acc); publish packed col-pairs.
    unsigned short* slot = ring + (size_t)(t & (RING_SLOTS - 1)) * BH;
    float hv[4];
    #pragma unroll
    for (int r = 0; r < 4; ++r) {
      int row = q * 4 + r;                                  // D row
      int xi = __shfl(xv, row);
      float av = (a0[r] + a1[r]) + (a2[r] + a3[r]);
      hv[r] = ftanh(proj[(size_t)xi * HID + hcol] + av);
      if (t == SEQ - 1) final_out[(size_t)(row0 + row) * HID + hcol] = hv[r];
    }
    #pragma unroll
    for (int r = 0; r < 4; ++r) {
      unsigned myb = f2bf(hv[r]);
      unsigned oth = (unsigned)__shfl_xor((int)myb, 1);
      if ((l15 & 1) == 0) {
        int b = row0 + q * 4 + r;
        unsigned short* p = slot + (size_t)b * HID + hcol;
        unsigned pk = myb | (oth << 16);
        if (mode) *(unsigned*)p = pk;     // XCD-local: dirty in local L2
        else      cstore32(p, pk);
      }
    }
    // 3) barrier arrive (drain releases stores to L2/MALL; counter at MALL)
    barrier_arrive(cnt_i, tid);
    // 4) logits lump in the barrier window: tsel <= t-1 (visible since the
    //    PREVIOUS round completed). Slot hazard: t - tsel in [1,16] < 32.
    if ((t & 15) == 15) {
      int tsel = (t - 16) + gj;
      if (tsel >= 0) {
        const unsigned short* hs =
            ring + (size_t)(tsel & (RING_SLOTS - 1)) * BH +
            (size_t)(row0 + l15) * HID + q * 8;             // A row base
        f32x4 lc = {0.f, 0.f, 0.f, 0.f};
        for (int g = 0; g < 4; ++g) {
          u64 hb[16];
          if (mode) {
            #pragma unroll
            for (int j = 0; j < 8; ++j) {
              const unsigned short* pk = hs + (g * 8 + j) * 32;
              hb[2 * j]     = ld64_sc0(pk);
              hb[2 * j + 1] = ld64_sc0(pk + 4);
            }
            asm volatile("s_waitcnt vmcnt(0)" ::: "memory");
            __builtin_amdgcn_sched_barrier(0);
          } else {
            #pragma unroll
            for (int j = 0; j < 8; ++j) {
              const unsigned short* pk = hs + (g * 8 + j) * 32;
              hb[2 * j]     = cload64(pk);
              hb[2 * j + 1] = cload64(pk + 4);
            }
          }
          #pragma unroll
          for (int j = 0; j < 8; ++j) {
            union { u64 d[2]; short8 s8; } c;
            c.d[0] = hb[2 * j]; c.d[1] = hb[2 * j + 1];
            short8 w8 = *(const short8*)(wofb + (size_t)(g * 8 + j) * 4096);
            lc = __builtin_amdgcn_mfma_f32_16x16x32_bf16(c.s8, w8, lc, 0, 0, 0);
          }
        }
        #pragma unroll
        for (int rr = 0; rr < 4; ++rr) {
          int b = row0 + q * 4 + rr;
          out[((size_t)b * SEQ + tsel) * VOC + wv * 16 + l15] = lc[rr] + bias;
        }
      }
    }
    barrier_wait(cnt_i, tid, t + 1);
    // 5) restage h_t (16 rows x 1024, coalesced) -> h_lds (2064 stride)
    if (t < SEQ - 1) {
      u64 tmp[16];
      if (mode) {
        #pragma unroll
        for (int rr = 0; rr < 16; ++rr)
          tmp[rr] = ld64_sc0(slot + (size_t)(row0 + rr) * HID + tid * 4);
        asm volatile("s_waitcnt vmcnt(0)" ::: "memory");
        __builtin_amdgcn_sched_barrier(0);
      } else {
        #pragma unroll
        for (int rr = 0; rr < 16; ++rr)
          tmp[rr] = cload64(slot + (size_t)(row0 + rr) * HID + tid * 4);
      }
      #pragma unroll
      for (int rr = 0; rr < 16; ++rr)
        *(u64*)(h_lds + rr * 2064 + tid * 8) = tmp[rr];
      __syncthreads();
    }
  }

  // ---- tail: tsel = 511 (only gj==15). Barrier round 512 completed ->
  //      slot 511 visible (MALL mode) / resident in our L2 (local mode).
  if (gj == 15) {
    int tsel = SEQ - 1;
    const unsigned short* hs =
        ring + (size_t)(tsel & (RING_SLOTS - 1)) * BH +
        (size_t)(row0 + l15) * HID + q * 8;
    f32x4 lc = {0.f, 0.f, 0.f, 0.f};
    for (int g = 0; g < 4; ++g) {
      u64 hb[16];
      if (mode) {
        #pragma unroll
        for (int j = 0; j < 8; ++j) {
          const unsigned short* pk = hs + (g * 8 + j) * 32;
          hb[2 * j]     = ld64_sc0(pk);
          hb[2 * j + 1] = ld64_sc0(pk + 4);
        }
        asm volatile("s_waitcnt vmcnt(0)" ::: "memory");
        __builtin_amdgcn_sched_barrier(0);
      } else {
        #pragma unroll
        for (int j = 0; j < 8; ++j) {
          const unsigned short* pk = hs + (g * 8 + j) * 32;
          hb[2 * j]     = cload64(pk);
          hb[2 * j + 1] = cload64(pk + 4);
        }
      }
      #pragma unroll
      for (int j = 0; j < 8; ++j) {
        union { u64 d[2]; short8 s8; } c;
        c.d[0] = hb[2 * j]; c.d[1] = hb[2 * j + 1];
        short8 w8 = *(const short8*)(wofb + (size_t)(g * 8 + j) * 4096);
        lc = __builtin_amdgcn_mfma_f32_16x16x32_bf16(c.s8, w8, lc, 0, 0, 0);
      }
    }
    #pragma unroll
    for (int rr = 0; rr < 4; ++rr) {
      int b = row0 + q * 4 + rr;
      out[((size_t)b * SEQ + tsel) * VOC + wv * 16 + l15] = lc[rr] + bias;
    }
  }
}

// ---------------- launch ----------------------------------------------------
extern "C" void kernel_launch(void* const* d_in, const int* in_sizes, int n_in,
                              void* d_out, int out_size, void* d_ws, size_t ws_size,
                              hipStream_t stream) {
  const int*   x   = (const int*)d_in[0];
  const float* emb = (const float*)d_in[1];
  const float* Wih = (const float*)d_in[2];
  const float* Whh = (const float*)d_in[3];
  const float* bh  = (const float*)d_in[4];
  const float* Who = (const float*)d_in[5];
  const float* bo  = (const float*)d_in[6];
  float* out = (float*)d_out;

  char* ws = (char*)d_ws;
  float*          proj = (float*)ws;                         // 262144 B
  unsigned int*   cnt  = (unsigned int*)(ws + 262144);       // 256KB region
  unsigned short* wof  = (unsigned short*)(ws + 524288);     // 131072 B
  unsigned short* ring = (unsigned short*)(ws + (1 << 20));  // 16 MiB

  size_t need = (size_t)(1 << 20) + (size_t)RING_SLOTS * BATCH * HID * 2;
  if (ws_size < need) return;  // diagnostic fail (absmax) instead of a fault

  (void)hipFuncSetAttribute(reinterpret_cast<const void*>(k_rnn),
                            hipFuncAttributeMaxDynamicSharedMemorySize, 131072);

  k_prep<<<256, 256, 0, stream>>>(emb, Wih, bh, proj);
  k_prep2<<<32, 256, 0, stream>>>(Who, wof);
  hipMemsetAsync(cnt, 0, 262144, stream);
  k_rnn<<<256, 256, 131072, stream>>>(x, Whh, proj, wof, bo, ring,
                                      out, out + FINAL_OFF, cnt);
}

// Round 15
// 1851.207 us; speedup vs baseline: 1.1798x; 1.1798x over previous
//
#include <hip/hip_runtime.h>
#include <stdint.h>

// CharRNN MI355X — r13 (champion, 1790us) + LAST-ARRIVER FAST-PATH barrier.
//   r14 post-mortem: XCD-local data path engaged (FETCH 150->79MB) but dur
//   WORSENED 1790->2150: the restage RTT it removes is NOT on the critical
//   path, and registration+vote cost ~360us/dispatch. Reverted entirely.
//   What binds instead: after the 16th barrier arrival, every member only
//   discovers completion at its NEXT poll round-trip (~900cy). atomicAdd
//   returns the old value -> the 16th arriver (the straggler = the critical
//   block) can detect `old == 16*round-1` from its own add and SKIP the
//   poll. Members with slack still poll; their observe latency is absorbed
//   by slack. Removes ~1 MALL RTT from the per-step critical chain.
//   Everything else byte-identical to r13: reg-resident W_hh B-frags
//   (128 VGPR), h_lds stride-2064 bank-clean, 16x64 geometry, ftanh,
//   4-chain accs, packed col-pair publish, wof table, logits lump in the
//   barrier window, channel-spread counters.
// d_ws: proj f32 @0 (256KB) | cnt @262144 (256KB, 8448B stride) |
//       wof @524288 (128KB) | ring bf16 @1MB (16MB)

#define BATCH 256
#define SEQ   512
#define HID   1024
#define VOC   64
#define EMB   256
#define FINAL_OFF (BATCH * SEQ * VOC)   // 8388608
#define RING_SLOTS 32
#define BH (BATCH * HID)
#define CNT_STRIDE 8448

typedef __attribute__((ext_vector_type(8))) short short8;
typedef __attribute__((ext_vector_type(4))) float f32x4;
typedef unsigned long long u64;

__device__ inline unsigned short f2bf(float f) {
  union { float f; unsigned u; } v; v.f = f;
  unsigned u = v.u;
  return (unsigned short)((u + 0x7FFFu + ((u >> 16) & 1u)) >> 16);  // RNE
}

// branch-free tanh: 1 - 2/(e^{2x}+1). Verified r7/r8/r12/r13.
__device__ __forceinline__ float ftanh(float v) {
  float e = __expf(2.0f * v);
  return fmaf(-2.0f, __builtin_amdgcn_rcpf(e + 1.0f), 1.0f);
}

// ---- agent-scope (MALL-point) ops — the PROVEN coherence class -------------
__device__ inline u64 cload64(const unsigned short* p) {
  return __hip_atomic_load((const u64*)p, __ATOMIC_RELAXED,
                           __HIP_MEMORY_SCOPE_AGENT);
}
__device__ inline void cstore32(unsigned short* p, unsigned v) {
  __hip_atomic_store((unsigned*)p, v, __ATOMIC_RELAXED,
                     __HIP_MEMORY_SCOPE_AGENT);
}

// ---------------- K1: projection table -------------------------------------
__global__ __launch_bounds__(256) void k_prep(const float* __restrict__ emb,
                                              const float* __restrict__ Wih,
                                              const float* __restrict__ bh,
                                              float* __restrict__ proj) {
  __shared__ float es[EMB];
  const int v = blockIdx.x >> 2;        // 0..63
  const int p = blockIdx.x & 3;         // h-quarter
  const int tid = threadIdx.x;
  es[tid] = emb[v * EMB + tid];
  __syncthreads();
  const int h = p * 256 + tid;
  float acc = bh[h];
  for (int e = 0; e < EMB; ++e) acc += es[e] * Wih[e * HID + h];
  proj[v * HID + h] = acc;
}

// ---------------- K1b: W_ho bf16 fragment table (r6+-proven) ----------------
// entry e = ((kb*4+q)*4+vt)*16 + l15 ; elems j: Who[(kb*32+q*8+j)*VOC+vt*16+l15]
__global__ __launch_bounds__(256) void k_prep2(const float* __restrict__ Who,
                                               unsigned short* __restrict__ wof) {
  const int e = blockIdx.x * 256 + threadIdx.x;   // 0..8191
  const int l15 = e & 15, vt = (e >> 4) & 3, qq = (e >> 6) & 3, kb = e >> 8;
  #pragma unroll
  for (int j = 0; j < 8; ++j)
    wof[e * 8 + j] = f2bf(Who[(kb * 32 + qq * 8 + j) * VOC + vt * 16 + l15]);
}

// ---------------- K2: persistent recurrence + inline logits ----------------
// LDS 131072: W_hh B-frag staging (dies) -> h_lds 16 x 2064B (bank-clean).
__global__ __launch_bounds__(256, 1) void k_rnn(
    const int* __restrict__ x, const float* __restrict__ Whh,
    const float* __restrict__ proj, const unsigned short* __restrict__ wof,
    const float* __restrict__ bo, unsigned short* __restrict__ ring,
    float* __restrict__ out, float* __restrict__ final_out,
    unsigned int* __restrict__ cnt) {
  extern __shared__ char smem[];
  unsigned short* w_lds = (unsigned short*)smem;            // staging (dies)
  char*           h_lds = smem;                             // reuses region

  const int tid = threadIdx.x, bid = blockIdx.x;
  const int gi = bid & 15, gj = bid >> 4;   // group (16 rows) / col-slice (64)
  const int row0 = gi * 16;
  const int lane = tid & 63, wv = tid >> 6;                 // wv = nt slice
  const int l15 = lane & 15, q = lane >> 4;

  // W_hh column slice (1024 x 64) -> LDS bf16 B-fragment order (staging).
  for (int it = 0; it < 256; ++it) {
    int u = it * 256 + tid;               // 0..65535
    int k = u >> 6, n = u & 63;           // coalesced over n
    int kb = k >> 5, qq = (k >> 3) & 3, j8 = k & 7;
    w_lds[(size_t)kb * 2048 + qq * 512 + n * 8 + j8] =
        f2bf(Whh[k * HID + gj * 64 + n]);
  }
  __syncthreads();

  // B-fragments -> REGISTERS (once; W_hh is step-invariant). 128 VGPR.
  short8 bfr[32];
  {
    const char* bbase = (const char*)w_lds + q * 1024 + (wv * 16 + l15) * 16;
    #pragma unroll
    for (int kb = 0; kb < 32; ++kb)
      bfr[kb] = *(const short8*)(bbase + (size_t)kb * 4096);
  }
  __syncthreads();                        // staging dead; region becomes h_lds

  unsigned int* cnt_i = (unsigned int*)((char*)cnt + gi * CNT_STRIDE);

  const int hcol = gj * 64 + wv * 16 + l15;
  const char* abase = h_lds + l15 * 2064 + q * 16;  // stride 2064: bank-clean
  const float bias = bo[wv * 16 + l15];
  const char* wofb = (const char*)wof + ((q * 4 + wv) * 16 + l15) * 16;

  for (int t = 0; t < SEQ; ++t) {
    int xv = (lane < 16) ? x[(row0 + lane) * SEQ + t] : 0;
    // 1) recurrence MFMA: 16x16 tile, K=1024; A from LDS, B from registers.
    f32x4 a0 = {0.f, 0.f, 0.f, 0.f}, a1 = {0.f, 0.f, 0.f, 0.f};
    f32x4 a2 = {0.f, 0.f, 0.f, 0.f}, a3 = {0.f, 0.f, 0.f, 0.f};
    if (t > 0) {
      #pragma unroll
      for (int kb = 0; kb < 32; kb += 4) {
        short8 af0 = *(const short8*)(abase + (kb + 0) * 64);
        a0 = __builtin_amdgcn_mfma_f32_16x16x32_bf16(af0, bfr[kb + 0], a0, 0, 0, 0);
        short8 af1 = *(const short8*)(abase + (kb + 1) * 64);
        a1 = __builtin_amdgcn_mfma_f32_16x16x32_bf16(af1, bfr[kb + 1], a1, 0, 0, 0);
        short8 af2 = *(const short8*)(abase + (kb + 2) * 64);
        a2 = __builtin_amdgcn_mfma_f32_16x16x32_bf16(af2, bfr[kb + 2], a2, 0, 0, 0);
        short8 af3 = *(const short8*)(abase + (kb + 3) * 64);
        a3 = __builtin_amdgcn_mfma_f32_16x16x32_bf16(af3, bfr[kb + 3], a3, 0, 0, 0);
      }
    }
    // 2) epilogue: h_t = tanh(proj[x_t] + acc); publish packed col-pairs.
    unsigned short* slot = ring + (size_t)(t & (RING_SLOTS - 1)) * BH;
    float hv[4];
    #pragma unroll
    for (int r = 0; r < 4; ++r) {
      int row = q * 4 + r;                                  // D row
      int xi = __shfl(xv, row);
      float av = (a0[r] + a1[r]) + (a2[r] + a3[r]);
      hv[r] = ftanh(proj[(size_t)xi * HID + hcol] + av);
      if (t == SEQ - 1) final_out[(size_t)(row0 + row) * HID + hcol] = hv[r];
    }
    #pragma unroll
    for (int r = 0; r < 4; ++r) {
      unsigned myb = f2bf(hv[r]);
      unsigned oth = (unsigned)__shfl_xor((int)myb, 1);
      if ((l15 & 1) == 0) {
        int b = row0 + q * 4 + r;
        cstore32(slot + (size_t)b * HID + hcol, myb | (oth << 16));
      }
    }
    // 3) barrier arrive: drain all waves' stores, then tid0 atomicAdd.
    //    FAST PATH: the returned old value tells the 16th arriver it is
    //    last -> it skips the poll (removes one MALL RTT from the critical
    //    member's chain). Others poll; their observe latency sits in slack.
    __syncthreads();                      // release: vmcnt(0) drain
    int last = 0;
    if (tid == 0) {
      unsigned old = atomicAdd(cnt_i, 1u);
      last = (old == 16u * (unsigned)(t + 1) - 1u);
    }
    // 4) logits lump in the barrier window: tsel <= t-1 (visible since the
    //    PREVIOUS round completed). Slot hazard: t - tsel in [1,16] < 32.
    if ((t & 15) == 15) {
      int tsel = (t - 16) + gj;
      if (tsel >= 0) {
        const unsigned short* hs =
            ring + (size_t)(tsel & (RING_SLOTS - 1)) * BH +
            (size_t)(row0 + l15) * HID + q * 8;             // A row base
        f32x4 lc = {0.f, 0.f, 0.f, 0.f};
        for (int g = 0; g < 4; ++g) {
          u64 hb[16];
          #pragma unroll
          for (int j = 0; j < 8; ++j) {
            const unsigned short* pk = hs + (g * 8 + j) * 32;
            hb[2 * j]     = cload64(pk);
            hb[2 * j + 1] = cload64(pk + 4);
          }
          #pragma unroll
          for (int j = 0; j < 8; ++j) {
            union { u64 d[2]; short8 s8; } c;
            c.d[0] = hb[2 * j]; c.d[1] = hb[2 * j + 1];
            short8 w8 = *(const short8*)(wofb + (size_t)(g * 8 + j) * 4096);
            lc = __builtin_amdgcn_mfma_f32_16x16x32_bf16(c.s8, w8, lc, 0, 0, 0);
          }
        }
        #pragma unroll
        for (int rr = 0; rr < 4; ++rr) {
          int b = row0 + q * 4 + rr;
          out[((size_t)b * SEQ + tsel) * VOC + wv * 16 + l15] = lc[rr] + bias;
        }
      }
    }
    // barrier wait (skipped by the last arriver)
    if (tid == 0 && !last) {
      int guard = 0;
      while (__hip_atomic_load(cnt_i, __ATOMIC_RELAXED,
                               __HIP_MEMORY_SCOPE_AGENT)
             < 16u * (unsigned)(t + 1)) {
        __builtin_amdgcn_s_sleep(1);
        if (++guard > (1 << 16)) break;  // bailout: wrong answer beats a hang
      }
    }
    __syncthreads();                      // acquire broadcast
    // 5) restage h_t (16 rows x 1024, coalesced agent loads) -> h_lds (2064)
    if (t < SEQ - 1) {
      u64 tmp[16];
      #pragma unroll
      for (int rr = 0; rr < 16; ++rr)
        tmp[rr] = cload64(slot + (size_t)(row0 + rr) * HID + tid * 4);
      #pragma unroll
      for (int rr = 0; rr < 16; ++rr)
        *(u64*)(h_lds + rr * 2064 + tid * 8) = tmp[rr];
      __syncthreads();
    }
  }

  // ---- tail: tsel = 511 (only gj==15). Barrier round 512 completed, so
  //      slot 511 is globally visible; no extra wait needed.
  if (gj == 15) {
    int tsel = SEQ - 1;
    const unsigned short* hs =
        ring + (size_t)(tsel & (RING_SLOTS - 1)) * BH +
        (size_t)(row0 + l15) * HID + q * 8;
    f32x4 lc = {0.f, 0.f, 0.f, 0.f};
    for (int g = 0; g < 4; ++g) {
      u64 hb[16];
      #pragma unroll
      for (int j = 0; j < 8; ++j) {
        const unsigned short* pk = hs + (g * 8 + j) * 32;
        hb[2 * j]     = cload64(pk);
        hb[2 * j + 1] = cload64(pk + 4);
      }
      #pragma unroll
      for (int j = 0; j < 8; ++j) {
        union { u64 d[2]; short8 s8; } c;
        c.d[0] = hb[2 * j]; c.d[1] = hb[2 * j + 1];
        short8 w8 = *(const short8*)(wofb + (size_t)(g * 8 + j) * 4096);
        lc = __builtin_amdgcn_mfma_f32_16x16x32_bf16(c.s8, w8, lc, 0, 0, 0);
      }
    }
    #pragma unroll
    for (int rr = 0; rr < 4; ++rr) {
      int b = row0 + q * 4 + rr;
      out[((size_t)b * SEQ + tsel) * VOC + wv * 16 + l15] = lc[rr] + bias;
    }
  }
}

// ---------------- launch ----------------------------------------------------
extern "C" void kernel_launch(void* const* d_in, const int* in_sizes, int n_in,
                              void* d_out, int out_size, void* d_ws, size_t ws_size,
                              hipStream_t stream) {
  const int*   x   = (const int*)d_in[0];
  const float* emb = (const float*)d_in[1];
  const float* Wih = (const float*)d_in[2];
  const float* Whh = (const float*)d_in[3];
  const float* bh  = (const float*)d_in[4];
  const float* Who = (const float*)d_in[5];
  const float* bo  = (const float*)d_in[6];
  float* out = (float*)d_out;

  char* ws = (char*)d_ws;
  float*          proj = (float*)ws;                         // 262144 B
  unsigned int*   cnt  = (unsigned int*)(ws + 262144);       // 256KB region
  unsigned short* wof  = (unsigned short*)(ws + 524288);     // 131072 B
  unsigned short* ring = (unsigned short*)(ws + (1 << 20));  // 16 MiB

  size_t need = (size_t)(1 << 20) + (size_t)RING_SLOTS * BATCH * HID * 2;
  if (ws_size < need) return;  // diagnostic fail (absmax) instead of a fault

  (void)hipFuncSetAttribute(reinterpret_cast<const void*>(k_rnn),
                            hipFuncAttributeMaxDynamicSharedMemorySize, 131072);

  k_prep<<<256, 256, 0, stream>>>(emb, Wih, bh, proj);
  k_prep2<<<32, 256, 0, stream>>>(Who, wof);
  hipMemsetAsync(cnt, 0, 262144, stream);
  k_rnn<<<256, 256, 131072, stream>>>(x, Whh, proj, wof, bo, ring,
                                      out, out + FINAL_OFF, cnt);
}

// Round 16
// 1706.987 us; speedup vs baseline: 1.2795x; 1.0845x over previous
//
#include <hip/hip_runtime.h>
#include <stdint.h>

// CharRNN MI355X — r13 (champion, 1790us) + LDS-RESIDENT proj & x.
//   r15 post-mortem: last-arriver barrier fast path null — the waiters'
//   observe-RTT gates the step, not the last arriver's poll. Sync levers
//   exhausted (8 rounds, all ±5%). Compute-side levers are what pay (r13:
//   −18%). This round removes the last serial GLOBAL latency from the
//   per-step chain: the epilogue's scattered proj[xi*HID+hcol] gather
//   (~1 uncovered L2/L3 RTT after the K-loop) and the per-step x load.
//   Both are small & block-resident: proj slice 64x64 f32 (16KB, padded to
//   65 floats/row vs 4-way q-group bank alias) and x slice transposed
//   xs_t[512][16] (32KB, conflict-free per-step read) now live in the LDS
//   freed by r13's reg-resident B-frags (33+16.6+32 = 82KB < 128KB).
//   Everything else byte-identical to r13: reg W_hh B-frags, h_lds 2064
//   stride, 16x64 geometry, split MALL counter barrier + logits window,
//   ftanh, 4-chain accs, packed publish, wof table.
// d_ws: proj f32 @0 (256KB) | cnt @262144 (256KB, 8448B stride) |
//       wof @524288 (128KB) | ring bf16 @1MB (16MB)

#define BATCH 256
#define SEQ   512
#define HID   1024
#define VOC   64
#define EMB   256
#define FINAL_OFF (BATCH * SEQ * VOC)   // 8388608
#define RING_SLOTS 32
#define BH (BATCH * HID)
#define CNT_STRIDE 8448

typedef __attribute__((ext_vector_type(8))) short short8;
typedef __attribute__((ext_vector_type(4))) float f32x4;
typedef unsigned long long u64;

__device__ inline unsigned short f2bf(float f) {
  union { float f; unsigned u; } v; v.f = f;
  unsigned u = v.u;
  return (unsigned short)((u + 0x7FFFu + ((u >> 16) & 1u)) >> 16);  // RNE
}

// branch-free tanh: 1 - 2/(e^{2x}+1). Verified r7/r8/r12/r13.
__device__ __forceinline__ float ftanh(float v) {
  float e = __expf(2.0f * v);
  return fmaf(-2.0f, __builtin_amdgcn_rcpf(e + 1.0f), 1.0f);
}

// ---- agent-scope (MALL-point) ops — the PROVEN coherence class -------------
__device__ inline u64 cload64(const unsigned short* p) {
  return __hip_atomic_load((const u64*)p, __ATOMIC_RELAXED,
                           __HIP_MEMORY_SCOPE_AGENT);
}
__device__ inline void cstore32(unsigned short* p, unsigned v) {
  __hip_atomic_store((unsigned*)p, v, __ATOMIC_RELAXED,
                     __HIP_MEMORY_SCOPE_AGENT);
}

// ---------------- K1: projection table -------------------------------------
__global__ __launch_bounds__(256) void k_prep(const float* __restrict__ emb,
                                              const float* __restrict__ Wih,
                                              const float* __restrict__ bh,
                                              float* __restrict__ proj) {
  __shared__ float es[EMB];
  const int v = blockIdx.x >> 2;        // 0..63
  const int p = blockIdx.x & 3;         // h-quarter
  const int tid = threadIdx.x;
  es[tid] = emb[v * EMB + tid];
  __syncthreads();
  const int h = p * 256 + tid;
  float acc = bh[h];
  for (int e = 0; e < EMB; ++e) acc += es[e] * Wih[e * HID + h];
  proj[v * HID + h] = acc;
}

// ---------------- K1b: W_ho bf16 fragment table (r6+-proven) ----------------
// entry e = ((kb*4+q)*4+vt)*16 + l15 ; elems j: Who[(kb*32+q*8+j)*VOC+vt*16+l15]
__global__ __launch_bounds__(256) void k_prep2(const float* __restrict__ Who,
                                               unsigned short* __restrict__ wof) {
  const int e = blockIdx.x * 256 + threadIdx.x;   // 0..8191
  const int l15 = e & 15, vt = (e >> 4) & 3, qq = (e >> 6) & 3, kb = e >> 8;
  #pragma unroll
  for (int j = 0; j < 8; ++j)
    wof[e * 8 + j] = f2bf(Who[(kb * 32 + qq * 8 + j) * VOC + vt * 16 + l15]);
}

// ---------------- K2: persistent recurrence + inline logits ----------------
// LDS 131072: W_hh B-frag staging (dies) ->
//   h_lds @0      16 x 2064B = 33024  (bank-clean A-reads)
//   p_lds @33024  64 x 65 f32 = 16640 (padded vs q-group alias)
//   xs_t  @49664  512 x 16 int = 32768 (transposed x, conflict-free)
__global__ __launch_bounds__(256, 1) void k_rnn(
    const int* __restrict__ x, const float* __restrict__ Whh,
    const float* __restrict__ proj, const unsigned short* __restrict__ wof,
    const float* __restrict__ bo, unsigned short* __restrict__ ring,
    float* __restrict__ out, float* __restrict__ final_out,
    unsigned int* __restrict__ cnt) {
  extern __shared__ char smem[];
  unsigned short* w_lds = (unsigned short*)smem;            // staging (dies)
  char*           h_lds = smem;                             // @0
  float*          p_lds = (float*)(smem + 33024);           // @33024
  int*            xs_t  = (int*)(smem + 49664);             // @49664

  const int tid = threadIdx.x, bid = blockIdx.x;
  const int gi = bid & 15, gj = bid >> 4;   // group (16 rows) / col-slice (64)
  const int row0 = gi * 16;
  const int lane = tid & 63, wv = tid >> 6;                 // wv = nt slice
  const int l15 = lane & 15, q = lane >> 4;

  // W_hh column slice (1024 x 64) -> LDS bf16 B-fragment order (staging).
  for (int it = 0; it < 256; ++it) {
    int u = it * 256 + tid;               // 0..65535
    int k = u >> 6, n = u & 63;           // coalesced over n
    int kb = k >> 5, qq = (k >> 3) & 3, j8 = k & 7;
    w_lds[(size_t)kb * 2048 + qq * 512 + n * 8 + j8] =
        f2bf(Whh[k * HID + gj * 64 + n]);
  }
  __syncthreads();

  // B-fragments -> REGISTERS (once; W_hh is step-invariant). 128 VGPR.
  short8 bfr[32];
  {
    const char* bbase = (const char*)w_lds + q * 1024 + (wv * 16 + l15) * 16;
    #pragma unroll
    for (int kb = 0; kb < 32; ++kb)
      bfr[kb] = *(const short8*)(bbase + (size_t)kb * 4096);
  }
  __syncthreads();                        // staging dead; region repurposed

  // LDS-resident proj slice (64 vocab x 64 cols, padded row 65 floats).
  for (int it = 0; it < 16; ++it) {
    int u = it * 256 + tid;               // 0..4095
    int v = u >> 6, c = u & 63;
    p_lds[v * 65 + c] = proj[(size_t)v * HID + gj * 64 + c];
  }
  // LDS-resident transposed x slice: xs_t[t][row].
  for (int it = 0; it < 32; ++it) {
    int u = it * 256 + tid;               // 0..8191
    int tt = u >> 4, r = u & 15;
    xs_t[tt * 16 + r] = x[(size_t)(row0 + r) * SEQ + tt];
  }
  __syncthreads();

  unsigned int* cnt_i = (unsigned int*)((char*)cnt + gi * CNT_STRIDE);

  const int hcol = gj * 64 + wv * 16 + l15;
  const int pcol = wv * 16 + l15;                   // col within p_lds row
  const char* abase = h_lds + l15 * 2064 + q * 16;  // stride 2064: bank-clean
  const float bias = bo[wv * 16 + l15];
  const char* wofb = (const char*)wof + ((q * 4 + wv) * 16 + l15) * 16;

  for (int t = 0; t < SEQ; ++t) {
    // 1) recurrence MFMA: 16x16 tile, K=1024; A from LDS, B from registers.
    f32x4 a0 = {0.f, 0.f, 0.f, 0.f}, a1 = {0.f, 0.f, 0.f, 0.f};
    f32x4 a2 = {0.f, 0.f, 0.f, 0.f}, a3 = {0.f, 0.f, 0.f, 0.f};
    if (t > 0) {
      #pragma unroll
      for (int kb = 0; kb < 32; kb += 4) {
        short8 af0 = *(const short8*)(abase + (kb + 0) * 64);
        a0 = __builtin_amdgcn_mfma_f32_16x16x32_bf16(af0, bfr[kb + 0], a0, 0, 0, 0);
        short8 af1 = *(const short8*)(abase + (kb + 1) * 64);
        a1 = __builtin_amdgcn_mfma_f32_16x16x32_bf16(af1, bfr[kb + 1], a1, 0, 0, 0);
        short8 af2 = *(const short8*)(abase + (kb + 2) * 64);
        a2 = __builtin_amdgcn_mfma_f32_16x16x32_bf16(af2, bfr[kb + 2], a2, 0, 0, 0);
        short8 af3 = *(const short8*)(abase + (kb + 3) * 64);
        a3 = __builtin_amdgcn_mfma_f32_16x16x32_bf16(af3, bfr[kb + 3], a3, 0, 0, 0);
      }
    }
    // 2) epilogue: h_t = tanh(proj[x_t] + acc) — ALL operands now in LDS.
    unsigned short* slot = ring + (size_t)(t & (RING_SLOTS - 1)) * BH;
    float hv[4];
    #pragma unroll
    for (int r = 0; r < 4; ++r) {
      int row = q * 4 + r;                                  // D row
      int xi = xs_t[t * 16 + row];                          // LDS broadcast
      float av = (a0[r] + a1[r]) + (a2[r] + a3[r]);
      hv[r] = ftanh(p_lds[xi * 65 + pcol] + av);
      if (t == SEQ - 1) final_out[(size_t)(row0 + row) * HID + hcol] = hv[r];
    }
    #pragma unroll
    for (int r = 0; r < 4; ++r) {
      unsigned myb = f2bf(hv[r]);
      unsigned oth = (unsigned)__shfl_xor((int)myb, 1);
      if ((l15 & 1) == 0) {
        int b = row0 + q * 4 + r;
        cstore32(slot + (size_t)b * HID + hcol, myb | (oth << 16));
      }
    }
    // 3) barrier arrive (drain + atomicAdd), then logits window, then wait.
    __syncthreads();                      // release: vmcnt(0) drain
    if (tid == 0) atomicAdd(cnt_i, 1u);
    // 4) logits lump in the barrier window: tsel <= t-1 (visible since the
    //    PREVIOUS round completed). Slot hazard: t - tsel in [1,16] < 32.
    if ((t & 15) == 15) {
      int tsel = (t - 16) + gj;
      if (tsel >= 0) {
        const unsigned short* hs =
            ring + (size_t)(tsel & (RING_SLOTS - 1)) * BH +
            (size_t)(row0 + l15) * HID + q * 8;             // A row base
        f32x4 lc = {0.f, 0.f, 0.f, 0.f};
        for (int g = 0; g < 4; ++g) {
          u64 hb[16];
          #pragma unroll
          for (int j = 0; j < 8; ++j) {
            const unsigned short* pk = hs + (g * 8 + j) * 32;
            hb[2 * j]     = cload64(pk);
            hb[2 * j + 1] = cload64(pk + 4);
          }
          #pragma unroll
          for (int j = 0; j < 8; ++j) {
            union { u64 d[2]; short8 s8; } c;
            c.d[0] = hb[2 * j]; c.d[1] = hb[2 * j + 1];
            short8 w8 = *(const short8*)(wofb + (size_t)(g * 8 + j) * 4096);
            lc = __builtin_amdgcn_mfma_f32_16x16x32_bf16(c.s8, w8, lc, 0, 0, 0);
          }
        }
        #pragma unroll
        for (int rr = 0; rr < 4; ++rr) {
          int b = row0 + q * 4 + rr;
          out[((size_t)b * SEQ + tsel) * VOC + wv * 16 + l15] = lc[rr] + bias;
        }
      }
    }
    // barrier wait
    if (tid == 0) {
      int guard = 0;
      while (__hip_atomic_load(cnt_i, __ATOMIC_RELAXED,
                               __HIP_MEMORY_SCOPE_AGENT)
             < 16u * (unsigned)(t + 1)) {
        __builtin_amdgcn_s_sleep(1);
        if (++guard > (1 << 16)) break;  // bailout: wrong answer beats a hang
      }
    }
    __syncthreads();                      // acquire broadcast
    // 5) restage h_t (16 rows x 1024, coalesced agent loads) -> h_lds (2064)
    if (t < SEQ - 1) {
      u64 tmp[16];
      #pragma unroll
      for (int rr = 0; rr < 16; ++rr)
        tmp[rr] = cload64(slot + (size_t)(row0 + rr) * HID + tid * 4);
      #pragma unroll
      for (int rr = 0; rr < 16; ++rr)
        *(u64*)(h_lds + rr * 2064 + tid * 8) = tmp[rr];
      __syncthreads();
    }
  }

  // ---- tail: tsel = 511 (only gj==15). Barrier round 512 completed, so
  //      slot 511 is globally visible; no extra wait needed.
  if (gj == 15) {
    int tsel = SEQ - 1;
    const unsigned short* hs =
        ring + (size_t)(tsel & (RING_SLOTS - 1)) * BH +
        (size_t)(row0 + l15) * HID + q * 8;
    f32x4 lc = {0.f, 0.f, 0.f, 0.f};
    for (int g = 0; g < 4; ++g) {
      u64 hb[16];
      #pragma unroll
      for (int j = 0; j < 8; ++j) {
        const unsigned short* pk = hs + (g * 8 + j) * 32;
        hb[2 * j]     = cload64(pk);
        hb[2 * j + 1] = cload64(pk + 4);
      }
      #pragma unroll
      for (int j = 0; j < 8; ++j) {
        union { u64 d[2]; short8 s8; } c;
        c.d[0] = hb[2 * j]; c.d[1] = hb[2 * j + 1];
        short8 w8 = *(const short8*)(wofb + (size_t)(g * 8 + j) * 4096);
        lc = __builtin_amdgcn_mfma_f32_16x16x32_bf16(c.s8, w8, lc, 0, 0, 0);
      }
    }
    #pragma unroll
    for (int rr = 0; rr < 4; ++rr) {
      int b = row0 + q * 4 + rr;
      out[((size_t)b * SEQ + tsel) * VOC + wv * 16 + l15] = lc[rr] + bias;
    }
  }
}

// ---------------- launch ----------------------------------------------------
extern "C" void kernel_launch(void* const* d_in, const int* in_sizes, int n_in,
                              void* d_out, int out_size, void* d_ws, size_t ws_size,
                              hipStream_t stream) {
  const int*   x   = (const int*)d_in[0];
  const float* emb = (const float*)d_in[1];
  const float* Wih = (const float*)d_in[2];
  const float* Whh = (const float*)d_in[3];
  const float* bh  = (const float*)d_in[4];
  const float* Who = (const float*)d_in[5];
  const float* bo  = (const float*)d_in[6];
  float* out = (float*)d_out;

  char* ws = (char*)d_ws;
  float*          proj = (float*)ws;                         // 262144 B
  unsigned int*   cnt  = (unsigned int*)(ws + 262144);       // 256KB region
  unsigned short* wof  = (unsigned short*)(ws + 524288);     // 131072 B
  unsigned short* ring = (unsigned short*)(ws + (1 << 20));  // 16 MiB

  size_t need = (size_t)(1 << 20) + (size_t)RING_SLOTS * BATCH * HID * 2;
  if (ws_size < need) return;  // diagnostic fail (absmax) instead of a fault

  (void)hipFuncSetAttribute(reinterpret_cast<const void*>(k_rnn),
                            hipFuncAttributeMaxDynamicSharedMemorySize, 131072);

  k_prep<<<256, 256, 0, stream>>>(emb, Wih, bh, proj);
  k_prep2<<<32, 256, 0, stream>>>(Who, wof);
  hipMemsetAsync(cnt, 0, 262144, stream);
  k_rnn<<<256, 256, 131072, stream>>>(x, Whh, proj, wof, bo, ring,
                                      out, out + FINAL_OFF, cnt);
}